// Round 35
// baseline (57.854 us; speedup 1.0000x reference)
//
#include <hip/hip_runtime.h>
#include <hip/hip_bf16.h>

#define B 2
#define S 2048
#define E 128
#define H 8
#define HD 16
#define BH (B*H)

#define RPB 4    // rows per block (qkv_proj)
#define KT 64    // key tile (attn)

typedef __attribute__((ext_vector_type(8))) short bf16x8;
typedef __attribute__((ext_vector_type(4))) float f32x4;

__device__ __forceinline__ unsigned short f2b(float f) {   // f32->bf16 RNE
    const unsigned u = __float_as_uint(f);
    return (unsigned short)((u + 0x7FFFu + ((u >> 16) & 1u)) >> 16);
}
__device__ __forceinline__ float b2f(unsigned short u) {
    return __uint_as_float((unsigned)u << 16);
}

// ---- Pass 0: QKV projection with INLINE mask compaction. ----
// Each wave redundantly ballot-scans its batch's mask (32 steps) to get the
// compact positions of this block's RPB rows + the keep-all fallback.
// K: Kx[bh][key][32] = hi dims | lo dims.  V: Bt[bh][key>>4][dim][32],
// slot = 2*(key&15)+part (interleaved hi/lo).
__global__ __launch_bounds__(384) void qkv_proj(
    const float* __restrict__ x,
    const float* __restrict__ wq,
    const float* __restrict__ wk,
    const float* __restrict__ wv,
    const int* __restrict__ mask,
    const int* __restrict__ masked_p,
    float* __restrict__ Q,
    unsigned short* __restrict__ Kxg, unsigned short* __restrict__ Btg)
{
    __shared__ float xs[RPB][E];
    const int row0 = blockIdx.x * RPB;
    const int b    = row0 >> 11;
    const int tid  = threadIdx.x;        // 0..383
    const int lane = tid & 63;
    const int mat  = tid >> 7;           // 0=q, 1=k, 2=v (wave-uniform)
    const int c    = tid & 127;          // output column

    for (int idx = tid; idx < RPB * E; idx += 384)
        ((float*)xs)[idx] = x[(size_t)row0 * E + idx];
    // no barrier yet: scan first (independent of xs)

    // inline compaction scan (per-wave redundant, identical results)
    const int masked = *masked_p;
    const int tchunk = (row0 & 2047) >> 6;   // 64-chunk holding our rows
    int base = 0, myval = -1;
    for (int it = 0; it < 32; ++it) {
        const bool keep = (masked != 0) || (mask[b * S + it * 64 + lane] != 0);
        const unsigned long long bal = __ballot(keep);
        if (it == tchunk)
            myval = keep ? base + (int)__popcll(bal & ((1ULL << lane) - 1ULL))
                         : -1;
        base += (int)__popcll(bal);
    }
    int posr[RPB];
    #pragma unroll
    for (int rr = 0; rr < RPB; ++rr)
        posr[rr] = __shfl(myval, (row0 + rr) & 63);
    if (base == 0) {                     // all masked: -1000 shift cancels
        #pragma unroll
        for (int rr = 0; rr < RPB; ++rr)
            posr[rr] = (row0 & 2047) + rr;
    }
    __syncthreads();                     // xs ready

    const float* w = (mat == 0) ? wq : (mat == 1) ? wk : wv;
    float a[RPB];
    #pragma unroll
    for (int rr = 0; rr < RPB; ++rr) a[rr] = 0.f;

    for (int i = 0; i < E; ++i) {
        const float wv_ = w[i * E + c];
        #pragma unroll
        for (int rr = 0; rr < RPB; ++rr)
            a[rr] = fmaf(xs[rr][i], wv_, a[rr]);
    }

    const int h = c & 7, d = c >> 3;     // faithful split: col = d*8+h
    if (mat == 0) {
        #pragma unroll
        for (int rr = 0; rr < RPB; ++rr) {
            const int s = (row0 & 2047) + rr;
            Q[(((size_t)(b * H + h)) * S + s) * HD + d] = a[rr] * 0.25f;
        }
    } else if (mat == 1) {
        #pragma unroll
        for (int rr = 0; rr < RPB; ++rr) {
            const int p_ = posr[rr];
            if (p_ >= 0) {
                const unsigned short kh = f2b(a[rr]);
                const unsigned short kl = f2b(a[rr] - b2f(kh));
                unsigned short* kx = Kxg + (size_t)(b * H + h) * S * 32
                                   + (size_t)p_ * 32;
                kx[d]      = kh;
                kx[16 + d] = kl;
            }
        }
    } else {
        #pragma unroll
        for (int rr = 0; rr < RPB; ++rr) {
            const int p_ = posr[rr];
            if (p_ >= 0) {
                const unsigned short vh = f2b(a[rr]);
                const unsigned short vl = f2b(a[rr] - b2f(vh));
                unsigned short* bt = Btg + (size_t)(b * H + h) * S * 32
                                   + ((size_t)(p_ >> 4) * 16 + d) * 32
                                   + (p_ & 15) * 2;
                *(unsigned*)bt = (unsigned)vh | ((unsigned)vl << 16);
            }
        }
    }
}

// ---- Pass 1: MFMA flash attention; inline cnt; in-register Bt tail. ----
// Kx tail garbage is harmless (sc overwritten before use); Bt tail fragments
// zeroed in-register on the last tile (0-valued B slots nullify any p).
__global__ __launch_bounds__(128, 4) void attn(
    const float* __restrict__ Q,
    const unsigned short* __restrict__ Kxg,
    const unsigned short* __restrict__ Btg,
    const int* __restrict__ mask,
    const int* __restrict__ masked_p,
    float* __restrict__ out)
{
    const int bh    = blockIdx.y;
    const int b     = bh >> 3;
    const int h     = bh & 7;
    const int qtile = blockIdx.x;        // 0..63
    const int tid   = threadIdx.x;       // 0..127
    const int wid   = tid >> 6;
    const int lane  = tid & 63;
    const int col   = lane & 15;
    const int g     = lane >> 4;         // 0..3
    const int qrow0 = qtile * 32 + wid * 16;

    // inline count of kept keys (uniform across lanes via ballot)
    int cn = 0;
    {
        const int masked = *masked_p;
        for (int it = 0; it < 32; ++it) {
            const bool keep = (masked != 0) ||
                              (mask[b * S + it * 64 + lane] != 0);
            cn += (int)__popcll(__ballot(keep));
        }
        if (cn == 0) cn = S;             // all masked: shift cancels
    }
    const int nt = (cn + KT - 1) >> 6;

    const unsigned short* KxB = Kxg + (size_t)bh * S * 32;
    const unsigned short* BtB = Btg + (size_t)bh * S * 32;

    bf16x8 qh, ql;
    {
        const float* qp = Q + ((size_t)bh * S + qrow0 + col) * HD + 8 * (g & 1);
        #pragma unroll
        for (int i = 0; i < 8; ++i) {
            const float f = qp[i];
            const unsigned short hi = f2b(f);
            qh[i] = (short)hi;
            ql[i] = (short)f2b(f - b2f(hi));
        }
    }

    float m = -1e30f, l = 0.f;
    f32x4 acc = {0.f, 0.f, 0.f, 0.f};

#define LOADT(KA, VB, TBASE)                                              \
    {                                                                     \
        const int base_ = (TBASE);                                        \
        _Pragma("unroll")                                                 \
        for (int kb = 0; kb < 4; ++kb) {                                  \
            KA[kb] = *(const bf16x8*)(                                    \
                KxB + (size_t)(base_ + kb * 16 + col) * 32 + 8 * g);      \
            VB[kb] = *(const bf16x8*)(                                    \
                BtB + (size_t)((base_ >> 4) + kb) * 512 + col * 32 + 8 * g); \
        }                                                                 \
        if (base_ + KT > cn) {           /* zero fake-key V slots */      \
            _Pragma("unroll")                                             \
            for (int kb = 0; kb < 4; ++kb)                                \
                _Pragma("unroll")                                         \
                for (int i = 0; i < 8; ++i)                               \
                    if (base_ + kb * 16 + 4 * g + (i >> 1) >= cn)         \
                        VB[kb][i] = 0;                                    \
        }                                                                 \
    }

#define COMPUTE(KA, VB, TBASE)                                            \
    {                                                                     \
        const int base_ = (TBASE);                                        \
        f32x4 sc[4];                                                      \
        _Pragma("unroll")                                                 \
        for (int kb = 0; kb < 4; ++kb) {                                  \
            f32x4 c_ = {0.f, 0.f, 0.f, 0.f};                              \
            c_ = __builtin_amdgcn_mfma_f32_16x16x32_bf16(KA[kb], qh, c_, 0, 0, 0); \
            c_ = __builtin_amdgcn_mfma_f32_16x16x32_bf16(KA[kb], ql, c_, 0, 0, 0); \
            sc[kb] = c_;                                                  \
        }                                                                 \
        if (base_ + KT > cn) {                                            \
            _Pragma("unroll")                                             \
            for (int kb = 0; kb < 4; ++kb)                                \
                _Pragma("unroll")                                         \
                for (int r = 0; r < 4; ++r)                               \
                    if (base_ + kb * 16 + 4 * g + r >= cn) sc[kb][r] = -1e30f; \
        }                                                                 \
        float tm = sc[0][0];                                              \
        _Pragma("unroll")                                                 \
        for (int kb = 0; kb < 4; ++kb)                                    \
            _Pragma("unroll")                                             \
            for (int r = 0; r < 4; ++r) tm = fmaxf(tm, sc[kb][r]);        \
        tm = fmaxf(tm, __shfl_xor(tm, 16));                               \
        tm = fmaxf(tm, __shfl_xor(tm, 32));                               \
        if (__any(tm > m)) {                                              \
            const float mn = fmaxf(m, tm);                                \
            const float alpha = __expf(m - mn);                           \
            m = mn;                                                       \
            l *= alpha;                                                   \
            _Pragma("unroll")                                             \
            for (int r = 0; r < 4; ++r)                                   \
                acc[r] *= __shfl(alpha, 4 * g + r);                       \
        }                                                                 \
        _Pragma("unroll")                                                 \
        for (int kb = 0; kb < 4; ++kb) {                                  \
            const float p0 = __expf(sc[kb][0] - m);                       \
            const float p1 = __expf(sc[kb][1] - m);                       \
            const float p2 = __expf(sc[kb][2] - m);                       \
            const float p3 = __expf(sc[kb][3] - m);                       \
            l += (p0 + p1) + (p2 + p3);                                   \
            union { unsigned u[4]; bf16x8 v; } pa;                        \
            const unsigned b0 = (unsigned)f2b(p0);                        \
            const unsigned b1 = (unsigned)f2b(p1);                        \
            const unsigned b2 = (unsigned)f2b(p2);                        \
            const unsigned b3 = (unsigned)f2b(p3);                        \
            pa.u[0] = b0 | (b0 << 16);                                    \
            pa.u[1] = b1 | (b1 << 16);                                    \
            pa.u[2] = b2 | (b2 << 16);                                    \
            pa.u[3] = b3 | (b3 << 16);                                    \
            acc = __builtin_amdgcn_mfma_f32_16x16x32_bf16(pa.v, VB[kb], acc, 0, 0, 0); \
        }                                                                 \
    }

    bf16x8 kaA[4], vbA[4], kaB[4], vbB[4];
    LOADT(kaA, vbA, 0);
    for (int kt = 0; kt < nt; kt += 2) {
        if (kt + 1 < nt) LOADT(kaB, vbB, (kt + 1) * KT);
        COMPUTE(kaA, vbA, kt * KT);
        if (kt + 1 < nt) {
            if (kt + 2 < nt) LOADT(kaA, vbA, (kt + 2) * KT);
            COMPUTE(kaB, vbB, (kt + 1) * KT);
        }
    }
#undef LOADT
#undef COMPUTE

    l += __shfl_xor(l, 16);
    l += __shfl_xor(l, 32);

    const float inv = 1.f / l;
    #pragma unroll
    for (int r = 0; r < 4; ++r) {
        const float ir = __shfl(inv, 4 * g + r);
        out[((size_t)(b * S + qrow0 + 4 * g + r)) * E + col * 8 + h] = acc[r] * ir;
    }
}

extern "C" void kernel_launch(void* const* d_in, const int* in_sizes, int n_in,
                              void* d_out, int out_size, void* d_ws, size_t ws_size,
                              hipStream_t stream) {
    int ix = 0, im0 = -1, isc = -1, iw[3] = {-1, -1, -1}, nw = 0;
    for (int i = 0; i < n_in; ++i) {
        const int sz = in_sizes[i];
        if (sz == B * S * E) ix = i;
        else if (sz == B * S) { if (im0 < 0) im0 = i; }
        else if (sz == E * E) { if (nw < 3) iw[nw++] = i; }
        else if (sz == 1 && isc < 0) isc = i;
    }
    if (im0 < 0) im0 = 1;
    if (isc < 0) isc = 3;
    if (nw < 3) { iw[0] = n_in - 3; iw[1] = n_in - 2; iw[2] = n_in - 1; }

    const float* x        = (const float*)d_in[ix];
    const int*   src_mask = (const int*)d_in[im0];
    const int*   masked_p = (const int*)d_in[isc];
    const float* wq       = (const float*)d_in[iw[0]];
    const float* wk       = (const float*)d_in[iw[1]];
    const float* wv       = (const float*)d_in[iw[2]];
    float*       out      = (float*)d_out;

    float*          Qw  = (float*)d_ws;
    unsigned short* Kxg = (unsigned short*)(Qw + (size_t)BH * S * HD);
    unsigned short* Btg = Kxg + (size_t)BH * S * 32;

    qkv_proj<<<B * S / RPB, 384, 0, stream>>>(
        x, wq, wk, wv, src_mask, masked_p, Qw, Kxg, Btg);
    attn<<<dim3(S / 32, BH), 128, 0, stream>>>(
        Qw, Kxg, Btg, src_mask, masked_p, out);
}

// Round 36
// 47.805 us; speedup vs baseline: 1.2102x; 1.2102x over previous
//
#include <hip/hip_runtime.h>
#include <hip/hip_bf16.h>

#define B 2
#define S 2048
#define E 128
#define H 8
#define HD 16
#define BH (B*H)

#define RPB 4    // rows per block (qkv_proj)
#define KT 64    // key tile (attn)

typedef __attribute__((ext_vector_type(8))) short bf16x8;
typedef __attribute__((ext_vector_type(4))) float f32x4;

__device__ __forceinline__ unsigned short f2b(float f) {   // f32->bf16 RNE
    const unsigned u = __float_as_uint(f);
    return (unsigned short)((u + 0x7FFFu + ((u >> 16) & 1u)) >> 16);
}
__device__ __forceinline__ float b2f(unsigned short u) {
    return __uint_as_float((unsigned)u << 16);
}

// ---- Pass A: compaction + tail-zero fused. Grid BH x 64 threads. ----
// Bt layout (INTERLEAVED): Bt[bh][key>>4][dim][32], slot = 2*(key&15)+part.
__global__ __launch_bounds__(64) void prep(
    const int* __restrict__ mask, const int* __restrict__ masked_p,
    int* __restrict__ pos, int* __restrict__ cnt,
    unsigned short* __restrict__ Kxg, unsigned short* __restrict__ Btg)
{
    const int bh = blockIdx.x;
    const int b = bh >> 3, h = bh & 7;
    const int lane = threadIdx.x;
    const int masked = *masked_p;

    int v[32];
    #pragma unroll
    for (int c = 0; c < 32; ++c)
        v[c] = mask[b * S + c * 64 + lane];

    int base = 0;
    #pragma unroll
    for (int c = 0; c < 32; ++c) {
        const bool keep = (masked != 0) || (v[c] != 0);
        const unsigned long long bal = __ballot(keep);
        if (h == 0) {
            const int my = base + (int)__popcll(bal & ((1ULL << lane) - 1ULL));
            pos[b * S + c * 64 + lane] = keep ? my : -1;
        }
        base += (int)__popcll(bal);
    }
    int cn = base;
    if (cn == 0) {                         // all masked: -1000 shift cancels
        if (h == 0) {
            #pragma unroll
            for (int c = 0; c < 32; ++c)
                pos[b * S + c * 64 + lane] = c * 64 + lane;
        }
        cn = S;
    }
    if (h == 0 && lane == 0) cnt[b] = cn;

    const int pad = ((cn + KT - 1) / KT) * KT;   // 64-granule
    const int nrows = pad - cn;
    unsigned short* KxB = Kxg + (size_t)bh * S * 32;
    unsigned short* BtB = Btg + (size_t)bh * S * 32;
    for (int idx = lane; idx < nrows * 16; idx += 64) {
        const int row = cn + (idx >> 4), d = idx & 15;
        KxB[row * 32 + d]      = 0;
        KxB[row * 32 + 16 + d] = 0;
        BtB[((row >> 4) * 16 + d) * 32 + (row & 15) * 2]     = 0;
        BtB[((row >> 4) * 16 + d) * 32 + (row & 15) * 2 + 1] = 0;
    }
}

// ---- Pass 0: QKV projection, 3-way matrix split, RPB=4 (1024 blocks). ----
__global__ __launch_bounds__(384) void qkv_proj(
    const float* __restrict__ x,
    const float* __restrict__ wq,
    const float* __restrict__ wk,
    const float* __restrict__ wv,
    const int* __restrict__ pos,
    float* __restrict__ Q,
    unsigned short* __restrict__ Kxg, unsigned short* __restrict__ Btg)
{
    __shared__ float xs[RPB][E];
    const int row0 = blockIdx.x * RPB;
    const int tid  = threadIdx.x;        // 0..383
    const int mat  = tid >> 7;           // 0=q, 1=k, 2=v (wave-uniform)
    const int c    = tid & 127;          // output column

    for (int idx = tid; idx < RPB * E; idx += 384)
        ((float*)xs)[idx] = x[(size_t)row0 * E + idx];
    __syncthreads();

    const float* w = (mat == 0) ? wq : (mat == 1) ? wk : wv;
    float a[RPB];
    #pragma unroll
    for (int rr = 0; rr < RPB; ++rr) a[rr] = 0.f;

    for (int i = 0; i < E; ++i) {
        const float wv_ = w[i * E + c];
        #pragma unroll
        for (int rr = 0; rr < RPB; ++rr)
            a[rr] = fmaf(xs[rr][i], wv_, a[rr]);
    }

    const int h = c & 7, d = c >> 3;     // faithful split: col = d*8+h
    if (mat == 0) {
        #pragma unroll
        for (int rr = 0; rr < RPB; ++rr) {
            const int row = row0 + rr;
            const int b = row >> 11, s = row & 2047;
            Q[(((size_t)(b * H + h)) * S + s) * HD + d] = a[rr] * 0.25f;
        }
    } else if (mat == 1) {
        #pragma unroll
        for (int rr = 0; rr < RPB; ++rr) {
            const int row = row0 + rr;
            const int p_ = pos[row];
            if (p_ >= 0) {
                const int b = row >> 11;
                const unsigned short kh = f2b(a[rr]);
                const unsigned short kl = f2b(a[rr] - b2f(kh));
                unsigned short* kx = Kxg + (size_t)(b * H + h) * S * 32
                                   + (size_t)p_ * 32;
                kx[d]      = kh;
                kx[16 + d] = kl;
            }
        }
    } else {
        #pragma unroll
        for (int rr = 0; rr < RPB; ++rr) {
            const int row = row0 + rr;
            const int p_ = pos[row];
            if (p_ >= 0) {
                const int b = row >> 11;
                const unsigned short vh = f2b(a[rr]);
                const unsigned short vl = f2b(a[rr] - b2f(vh));
                unsigned short* bt = Btg + (size_t)(b * H + h) * S * 32
                                   + ((size_t)(p_ >> 4) * 16 + d) * 32
                                   + (p_ & 15) * 2;
                *(unsigned*)bt = (unsigned)vh | ((unsigned)vl << 16);
            }
        }
    }
}

// ---- Pass 1: MFMA flash attention, KT=64, VGPR capped for 4 waves/EU. ----
__global__ __launch_bounds__(128, 4) void attn(
    const float* __restrict__ Q,
    const unsigned short* __restrict__ Kxg,
    const unsigned short* __restrict__ Btg,
    const int* __restrict__ cnt,
    float* __restrict__ out)
{
    const int bh    = blockIdx.y;
    const int b     = bh >> 3;
    const int h     = bh & 7;
    const int qtile = blockIdx.x;        // 0..63
    const int tid   = threadIdx.x;       // 0..127
    const int wid   = tid >> 6;
    const int lane  = tid & 63;
    const int col   = lane & 15;
    const int g     = lane >> 4;         // 0..3
    const int qrow0 = qtile * 32 + wid * 16;
    const int cn    = cnt[b];
    const int nt    = (cn + KT - 1) >> 6;

    const unsigned short* KxB = Kxg + (size_t)bh * S * 32;
    const unsigned short* BtB = Btg + (size_t)bh * S * 32;

    bf16x8 qh, ql;
    {
        const float* qp = Q + ((size_t)bh * S + qrow0 + col) * HD + 8 * (g & 1);
        #pragma unroll
        for (int i = 0; i < 8; ++i) {
            const float f = qp[i];
            const unsigned short hi = f2b(f);
            qh[i] = (short)hi;
            ql[i] = (short)f2b(f - b2f(hi));
        }
    }

    float m = -1e30f, l = 0.f;
    f32x4 acc = {0.f, 0.f, 0.f, 0.f};

#define LOADT(KA, VB, TBASE)                                              \
    {                                                                     \
        const int base_ = (TBASE);                                        \
        _Pragma("unroll")                                                 \
        for (int kb = 0; kb < 4; ++kb) {                                  \
            KA[kb] = *(const bf16x8*)(                                    \
                KxB + (size_t)(base_ + kb * 16 + col) * 32 + 8 * g);      \
            VB[kb] = *(const bf16x8*)(                                    \
                BtB + (size_t)((base_ >> 4) + kb) * 512 + col * 32 + 8 * g); \
        }                                                                 \
    }

#define COMPUTE(KA, VB, TBASE)                                            \
    {                                                                     \
        const int base_ = (TBASE);                                        \
        f32x4 sc[4];                                                      \
        _Pragma("unroll")                                                 \
        for (int kb = 0; kb < 4; ++kb) {                                  \
            f32x4 c_ = {0.f, 0.f, 0.f, 0.f};                              \
            c_ = __builtin_amdgcn_mfma_f32_16x16x32_bf16(KA[kb], qh, c_, 0, 0, 0); \
            c_ = __builtin_amdgcn_mfma_f32_16x16x32_bf16(KA[kb], ql, c_, 0, 0, 0); \
            sc[kb] = c_;                                                  \
        }                                                                 \
        if (base_ + KT > cn) {                                            \
            _Pragma("unroll")                                             \
            for (int kb = 0; kb < 4; ++kb)                                \
                _Pragma("unroll")                                         \
                for (int r = 0; r < 4; ++r)                               \
                    if (base_ + kb * 16 + 4 * g + r >= cn) sc[kb][r] = -1e30f; \
        }                                                                 \
        float tm = sc[0][0];                                              \
        _Pragma("unroll")                                                 \
        for (int kb = 0; kb < 4; ++kb)                                    \
            _Pragma("unroll")                                             \
            for (int r = 0; r < 4; ++r) tm = fmaxf(tm, sc[kb][r]);        \
        tm = fmaxf(tm, __shfl_xor(tm, 16));                               \
        tm = fmaxf(tm, __shfl_xor(tm, 32));                               \
        if (__any(tm > m)) {                                              \
            const float mn = fmaxf(m, tm);                                \
            const float alpha = __expf(m - mn);                           \
            m = mn;                                                       \
            l *= alpha;                                                   \
            _Pragma("unroll")                                             \
            for (int r = 0; r < 4; ++r)                                   \
                acc[r] *= __shfl(alpha, 4 * g + r);                       \
        }                                                                 \
        _Pragma("unroll")                                                 \
        for (int kb = 0; kb < 4; ++kb) {                                  \
            const float p0 = __expf(sc[kb][0] - m);                       \
            const float p1 = __expf(sc[kb][1] - m);                       \
            const float p2 = __expf(sc[kb][2] - m);                       \
            const float p3 = __expf(sc[kb][3] - m);                       \
            l += (p0 + p1) + (p2 + p3);                                   \
            union { unsigned u[4]; bf16x8 v; } pa;                        \
            const unsigned b0 = (unsigned)f2b(p0);                        \
            const unsigned b1 = (unsigned)f2b(p1);                        \
            const unsigned b2 = (unsigned)f2b(p2);                        \
            const unsigned b3 = (unsigned)f2b(p3);                        \
            pa.u[0] = b0 | (b0 << 16);                                    \
            pa.u[1] = b1 | (b1 << 16);                                    \
            pa.u[2] = b2 | (b2 << 16);                                    \
            pa.u[3] = b3 | (b3 << 16);                                    \
            acc = __builtin_amdgcn_mfma_f32_16x16x32_bf16(pa.v, VB[kb], acc, 0, 0, 0); \
        }                                                                 \
    }

    bf16x8 kaA[4], vbA[4], kaB[4], vbB[4];
    LOADT(kaA, vbA, 0);
    for (int kt = 0; kt < nt; kt += 2) {
        if (kt + 1 < nt) LOADT(kaB, vbB, (kt + 1) * KT);
        COMPUTE(kaA, vbA, kt * KT);
        if (kt + 1 < nt) {
            if (kt + 2 < nt) LOADT(kaA, vbA, (kt + 2) * KT);
            COMPUTE(kaB, vbB, (kt + 1) * KT);
        }
    }
#undef LOADT
#undef COMPUTE

    l += __shfl_xor(l, 16);
    l += __shfl_xor(l, 32);

    const float inv = 1.f / l;
    #pragma unroll
    for (int r = 0; r < 4; ++r) {
        const float ir = __shfl(inv, 4 * g + r);
        out[((size_t)(b * S + qrow0 + 4 * g + r)) * E + col * 8 + h] = acc[r] * ir;
    }
}

extern "C" void kernel_launch(void* const* d_in, const int* in_sizes, int n_in,
                              void* d_out, int out_size, void* d_ws, size_t ws_size,
                              hipStream_t stream) {
    int ix = 0, im0 = -1, isc = -1, iw[3] = {-1, -1, -1}, nw = 0;
    for (int i = 0; i < n_in; ++i) {
        const int sz = in_sizes[i];
        if (sz == B * S * E) ix = i;
        else if (sz == B * S) { if (im0 < 0) im0 = i; }
        else if (sz == E * E) { if (nw < 3) iw[nw++] = i; }
        else if (sz == 1 && isc < 0) isc = i;
    }
    if (im0 < 0) im0 = 1;
    if (isc < 0) isc = 3;
    if (nw < 3) { iw[0] = n_in - 3; iw[1] = n_in - 2; iw[2] = n_in - 1; }

    const float* x        = (const float*)d_in[ix];
    const int*   src_mask = (const int*)d_in[im0];
    const int*   masked_p = (const int*)d_in[isc];
    const float* wq       = (const float*)d_in[iw[0]];
    const float* wk       = (const float*)d_in[iw[1]];
    const float* wv       = (const float*)d_in[iw[2]];
    float*       out      = (float*)d_out;

    float*          Qw  = (float*)d_ws;
    unsigned short* Kxg = (unsigned short*)(Qw + (size_t)BH * S * HD);
    unsigned short* Btg = Kxg + (size_t)BH * S * 32;
    int*            pos = (int*)(Btg + (size_t)BH * S * 32);
    int*            cnt = pos + B * S;

    prep<<<BH, 64, 0, stream>>>(src_mask, masked_p, pos, cnt, Kxg, Btg);
    qkv_proj<<<B * S / RPB, 384, 0, stream>>>(x, wq, wk, wv, pos, Qw, Kxg, Btg);
    attn<<<dim3(S / 32, BH), 128, 0, stream>>>(Qw, Kxg, Btg, cnt, out);
}

// Round 37
// 47.034 us; speedup vs baseline: 1.2300x; 1.0164x over previous
//
#include <hip/hip_runtime.h>
#include <hip/hip_bf16.h>

#define B 2
#define S 2048
#define E 128
#define H 8
#define HD 16
#define BH (B*H)

#define RPB 4    // rows per block (qkv_proj)
#define KT 64    // key tile (attn)
#define LP 40    // padded LDS row stride in u16 (80 B; banks walk 20 -> 2-way)

typedef __attribute__((ext_vector_type(8))) short bf16x8;
typedef __attribute__((ext_vector_type(4))) float f32x4;

__device__ __forceinline__ unsigned short f2b(float f) {   // f32->bf16 RNE
    const unsigned u = __float_as_uint(f);
    return (unsigned short)((u + 0x7FFFu + ((u >> 16) & 1u)) >> 16);
}
__device__ __forceinline__ float b2f(unsigned short u) {
    return __uint_as_float((unsigned)u << 16);
}

// ---- Pass A: compaction + tail-zero fused. Grid BH x 64 threads. ----
// Bt layout (INTERLEAVED): Bt[bh][key>>4][dim][32], slot = 2*(key&15)+part.
__global__ __launch_bounds__(64) void prep(
    const int* __restrict__ mask, const int* __restrict__ masked_p,
    int* __restrict__ pos, int* __restrict__ cnt,
    unsigned short* __restrict__ Kxg, unsigned short* __restrict__ Btg)
{
    const int bh = blockIdx.x;
    const int b = bh >> 3, h = bh & 7;
    const int lane = threadIdx.x;
    const int masked = *masked_p;

    int v[32];
    #pragma unroll
    for (int c = 0; c < 32; ++c)
        v[c] = mask[b * S + c * 64 + lane];

    int base = 0;
    #pragma unroll
    for (int c = 0; c < 32; ++c) {
        const bool keep = (masked != 0) || (v[c] != 0);
        const unsigned long long bal = __ballot(keep);
        if (h == 0) {
            const int my = base + (int)__popcll(bal & ((1ULL << lane) - 1ULL));
            pos[b * S + c * 64 + lane] = keep ? my : -1;
        }
        base += (int)__popcll(bal);
    }
    int cn = base;
    if (cn == 0) {                         // all masked: -1000 shift cancels
        if (h == 0) {
            #pragma unroll
            for (int c = 0; c < 32; ++c)
                pos[b * S + c * 64 + lane] = c * 64 + lane;
        }
        cn = S;
    }
    if (h == 0 && lane == 0) cnt[b] = cn;

    const int pad = ((cn + KT - 1) / KT) * KT;   // 64-granule
    const int nrows = pad - cn;
    unsigned short* KxB = Kxg + (size_t)bh * S * 32;
    unsigned short* BtB = Btg + (size_t)bh * S * 32;
    for (int idx = lane; idx < nrows * 16; idx += 64) {
        const int row = cn + (idx >> 4), d = idx & 15;
        KxB[row * 32 + d]      = 0;
        KxB[row * 32 + 16 + d] = 0;
        BtB[((row >> 4) * 16 + d) * 32 + (row & 15) * 2]     = 0;
        BtB[((row >> 4) * 16 + d) * 32 + (row & 15) * 2 + 1] = 0;
    }
}

// ---- Pass 0: QKV projection, 3-way matrix split, RPB=4 (1024 blocks). ----
__global__ __launch_bounds__(384) void qkv_proj(
    const float* __restrict__ x,
    const float* __restrict__ wq,
    const float* __restrict__ wk,
    const float* __restrict__ wv,
    const int* __restrict__ pos,
    float* __restrict__ Q,
    unsigned short* __restrict__ Kxg, unsigned short* __restrict__ Btg)
{
    __shared__ float xs[RPB][E];
    const int row0 = blockIdx.x * RPB;
    const int tid  = threadIdx.x;        // 0..383
    const int mat  = tid >> 7;           // 0=q, 1=k, 2=v (wave-uniform)
    const int c    = tid & 127;          // output column

    for (int idx = tid; idx < RPB * E; idx += 384)
        ((float*)xs)[idx] = x[(size_t)row0 * E + idx];
    __syncthreads();

    const float* w = (mat == 0) ? wq : (mat == 1) ? wk : wv;
    float a[RPB];
    #pragma unroll
    for (int rr = 0; rr < RPB; ++rr) a[rr] = 0.f;

    for (int i = 0; i < E; ++i) {
        const float wv_ = w[i * E + c];
        #pragma unroll
        for (int rr = 0; rr < RPB; ++rr)
            a[rr] = fmaf(xs[rr][i], wv_, a[rr]);
    }

    const int h = c & 7, d = c >> 3;     // faithful split: col = d*8+h
    if (mat == 0) {
        #pragma unroll
        for (int rr = 0; rr < RPB; ++rr) {
            const int row = row0 + rr;
            const int b = row >> 11, s = row & 2047;
            Q[(((size_t)(b * H + h)) * S + s) * HD + d] = a[rr] * 0.25f;
        }
    } else if (mat == 1) {
        #pragma unroll
        for (int rr = 0; rr < RPB; ++rr) {
            const int row = row0 + rr;
            const int p_ = pos[row];
            if (p_ >= 0) {
                const int b = row >> 11;
                const unsigned short kh = f2b(a[rr]);
                const unsigned short kl = f2b(a[rr] - b2f(kh));
                unsigned short* kx = Kxg + (size_t)(b * H + h) * S * 32
                                   + (size_t)p_ * 32;
                kx[d]      = kh;
                kx[16 + d] = kl;
            }
        }
    } else {
        #pragma unroll
        for (int rr = 0; rr < RPB; ++rr) {
            const int row = row0 + rr;
            const int p_ = pos[row];
            if (p_ >= 0) {
                const int b = row >> 11;
                const unsigned short vh = f2b(a[rr]);
                const unsigned short vl = f2b(a[rr] - b2f(vh));
                unsigned short* bt = Btg + (size_t)(b * H + h) * S * 32
                                   + ((size_t)(p_ >> 4) * 16 + d) * 32
                                   + (p_ & 15) * 2;
                *(unsigned*)bt = (unsigned)vh | ((unsigned)vl << 16);
            }
        }
    }
}

// ---- Pass 1: MFMA flash attention, LDS-shared K/V stream (4 waves). ----
// Block 256 = 4 waves x 16 queries; per tile the 8 KB packed Kx/Bt tile is
// staged once into double-buffered padded LDS and read by all 4 waves
// (L2 traffic /4). T14 split: global loads issue before COMPUTE, ds_writes
// after. Tail rows are pre-zeroed in ws by prep.
__global__ __launch_bounds__(256) void attn(
    const float* __restrict__ Q,
    const unsigned short* __restrict__ Kxg,
    const unsigned short* __restrict__ Btg,
    const int* __restrict__ cnt,
    float* __restrict__ out)
{
    __shared__ unsigned short Ks[2][KT * LP];
    __shared__ unsigned short Bs[2][KT * LP];

    const int bh    = blockIdx.y;
    const int b     = bh >> 3;
    const int h     = bh & 7;
    const int qtile = blockIdx.x;        // 0..31
    const int tid   = threadIdx.x;       // 0..255
    const int wid   = tid >> 6;          // 0..3
    const int lane  = tid & 63;
    const int col   = lane & 15;
    const int g     = lane >> 4;         // 0..3
    const int qrow0 = qtile * 64 + wid * 16;
    const int cn    = cnt[b];
    const int nt    = (cn + KT - 1) >> 6;

    const unsigned short* KxB = Kxg + (size_t)bh * S * 32;
    const unsigned short* BtB = Btg + (size_t)bh * S * 32;

    // staging map: thread t handles 16B quarter-row srow = t>>2, sc4 = t&3
    const int srow = tid >> 2;           // 0..63
    const int sc4  = tid & 3;            // 0..3
    const int soff = srow * 32 + sc4 * 8;     // u16 offset within 4 KB tile
    const int doff = srow * LP + sc4 * 8;     // padded LDS u16 offset

    bf16x8 qh, ql;
    {
        const float* qp = Q + ((size_t)bh * S + qrow0 + col) * HD + 8 * (g & 1);
        #pragma unroll
        for (int i = 0; i < 8; ++i) {
            const float f = qp[i];
            const unsigned short hi = f2b(f);
            qh[i] = (short)hi;
            ql[i] = (short)f2b(f - b2f(hi));
        }
    }

    float m = -1e30f, l = 0.f;
    f32x4 acc = {0.f, 0.f, 0.f, 0.f};

#define COMPUTE(BUF, TBASE)                                               \
    {                                                                     \
        const int base_ = (TBASE);                                        \
        f32x4 sc[4];                                                      \
        _Pragma("unroll")                                                 \
        for (int kb = 0; kb < 4; ++kb) {                                  \
            const bf16x8 ka = *(const bf16x8*)&Ks[BUF][(kb * 16 + col) * LP + 8 * g]; \
            f32x4 c_ = {0.f, 0.f, 0.f, 0.f};                              \
            c_ = __builtin_amdgcn_mfma_f32_16x16x32_bf16(ka, qh, c_, 0, 0, 0); \
            c_ = __builtin_amdgcn_mfma_f32_16x16x32_bf16(ka, ql, c_, 0, 0, 0); \
            sc[kb] = c_;                                                  \
        }                                                                 \
        if (base_ + KT > cn) {                                            \
            _Pragma("unroll")                                             \
            for (int kb = 0; kb < 4; ++kb)                                \
                _Pragma("unroll")                                         \
                for (int r = 0; r < 4; ++r)                               \
                    if (base_ + kb * 16 + 4 * g + r >= cn) sc[kb][r] = -1e30f; \
        }                                                                 \
        float tm = sc[0][0];                                              \
        _Pragma("unroll")                                                 \
        for (int kb = 0; kb < 4; ++kb)                                    \
            _Pragma("unroll")                                             \
            for (int r = 0; r < 4; ++r) tm = fmaxf(tm, sc[kb][r]);        \
        tm = fmaxf(tm, __shfl_xor(tm, 16));                               \
        tm = fmaxf(tm, __shfl_xor(tm, 32));                               \
        if (__any(tm > m)) {                                              \
            const float mn = fmaxf(m, tm);                                \
            const float alpha = __expf(m - mn);                           \
            m = mn;                                                       \
            l *= alpha;                                                   \
            _Pragma("unroll")                                             \
            for (int r = 0; r < 4; ++r)                                   \
                acc[r] *= __shfl(alpha, 4 * g + r);                       \
        }                                                                 \
        _Pragma("unroll")                                                 \
        for (int kb = 0; kb < 4; ++kb) {                                  \
            const float p0 = __expf(sc[kb][0] - m);                       \
            const float p1 = __expf(sc[kb][1] - m);                       \
            const float p2 = __expf(sc[kb][2] - m);                       \
            const float p3 = __expf(sc[kb][3] - m);                       \
            l += (p0 + p1) + (p2 + p3);                                   \
            union { unsigned u[4]; bf16x8 v; } pa;                        \
            const unsigned b0 = (unsigned)f2b(p0);                        \
            const unsigned b1 = (unsigned)f2b(p1);                        \
            const unsigned b2 = (unsigned)f2b(p2);                        \
            const unsigned b3 = (unsigned)f2b(p3);                        \
            pa.u[0] = b0 | (b0 << 16);                                    \
            pa.u[1] = b1 | (b1 << 16);                                    \
            pa.u[2] = b2 | (b2 << 16);                                    \
            pa.u[3] = b3 | (b3 << 16);                                    \
            const bf16x8 vb = *(const bf16x8*)&Bs[BUF][(kb * 16 + col) * LP + 8 * g]; \
            acc = __builtin_amdgcn_mfma_f32_16x16x32_bf16(pa.v, vb, acc, 0, 0, 0); \
        }                                                                 \
    }

    // prologue: stage tile 0 into buf 0
    {
        const bf16x8 k0 = *(const bf16x8*)(KxB + soff);
        const bf16x8 v0 = *(const bf16x8*)(BtB + soff);
        *(bf16x8*)&Ks[0][doff] = k0;
        *(bf16x8*)&Bs[0][doff] = v0;
    }
    __syncthreads();

    for (int kt = 0; kt < nt; ++kt) {
        const int cur = kt & 1;
        bf16x8 kN, vN;
        const bool more = (kt + 1 < nt);
        if (more) {                       // issue next-tile loads EARLY
            const size_t tb = (size_t)(kt + 1) * 2048 + soff;
            kN = *(const bf16x8*)(KxB + tb);
            vN = *(const bf16x8*)(BtB + tb);
        }
        COMPUTE(cur, kt * KT);
        if (more) {                       // write LATE (latency hidden)
            *(bf16x8*)&Ks[cur ^ 1][doff] = kN;
            *(bf16x8*)&Bs[cur ^ 1][doff] = vN;
        }
        __syncthreads();
    }
#undef COMPUTE

    l += __shfl_xor(l, 16);
    l += __shfl_xor(l, 32);

    const float inv = 1.f / l;
    #pragma unroll
    for (int r = 0; r < 4; ++r) {
        const float ir = __shfl(inv, 4 * g + r);
        out[((size_t)(b * S + qrow0 + 4 * g + r)) * E + col * 8 + h] = acc[r] * ir;
    }
}

extern "C" void kernel_launch(void* const* d_in, const int* in_sizes, int n_in,
                              void* d_out, int out_size, void* d_ws, size_t ws_size,
                              hipStream_t stream) {
    int ix = 0, im0 = -1, isc = -1, iw[3] = {-1, -1, -1}, nw = 0;
    for (int i = 0; i < n_in; ++i) {
        const int sz = in_sizes[i];
        if (sz == B * S * E) ix = i;
        else if (sz == B * S) { if (im0 < 0) im0 = i; }
        else if (sz == E * E) { if (nw < 3) iw[nw++] = i; }
        else if (sz == 1 && isc < 0) isc = i;
    }
    if (im0 < 0) im0 = 1;
    if (isc < 0) isc = 3;
    if (nw < 3) { iw[0] = n_in - 3; iw[1] = n_in - 2; iw[2] = n_in - 1; }

    const float* x        = (const float*)d_in[ix];
    const int*   src_mask = (const int*)d_in[im0];
    const int*   masked_p = (const int*)d_in[isc];
    const float* wq       = (const float*)d_in[iw[0]];
    const float* wk       = (const float*)d_in[iw[1]];
    const float* wv       = (const float*)d_in[iw[2]];
    float*       out      = (float*)d_out;

    float*          Qw  = (float*)d_ws;
    unsigned short* Kxg = (unsigned short*)(Qw + (size_t)BH * S * HD);
    unsigned short* Btg = Kxg + (size_t)BH * S * 32;
    int*            pos = (int*)(Btg + (size_t)BH * S * 32);
    int*            cnt = pos + B * S;

    prep<<<BH, 64, 0, stream>>>(src_mask, masked_p, pos, cnt, Kxg, Btg);
    qkv_proj<<<B * S / RPB, 384, 0, stream>>>(x, wq, wk, wv, pos, Qw, Kxg, Btg);
    attn<<<dim3(S / 64, BH), 256, 0, stream>>>(Qw, Kxg, Btg, cnt, out);
}